// Round 6
// baseline (303.356 us; speedup 1.0000x reference)
//
#include <hip/hip_runtime.h>
#include <hip/hip_cooperative_groups.h>

namespace cg = cooperative_groups;

#define HID 128
#define NN  256
#define BB  8
#define NCATS 64

// ---------------------------------------------------------------------------
// bf16 pack/unpack (RNE rounding on pack)
__device__ inline unsigned pack_bf16(float lo, float hi) {
    unsigned ul = __float_as_uint(lo);
    unsigned uh = __float_as_uint(hi);
    ul = (ul + 0x7fffu + ((ul >> 16) & 1u)) >> 16;
    uh = (uh + 0x7fffu + ((uh >> 16) & 1u)) & 0xffff0000u;
    return ul | uh;
}
__device__ inline float bf_lo(unsigned v) { return __uint_as_float(v << 16); }
__device__ inline float bf_hi(unsigned v) { return __uint_as_float(v & 0xffff0000u); }

// Wave-per-row LN reduction (row split as a=dim[lane], c=dim[lane+64]).
__device__ inline void ln_stats(float a, float c, float& mean, float& rs) {
    float s = a + c;
    float q = a * a + c * c;
    #pragma unroll
    for (int m = 32; m; m >>= 1) {
        s += __shfl_xor(s, m);
        q += __shfl_xor(q, m);
    }
    mean = s * (1.0f / 128.0f);
    float var = q * (1.0f / 128.0f) - mean * mean;
    rs = rsqrtf(var + 1e-5f);
}

struct KArgs {
    const float* x; const float* emb;
    const float* inW1; const float* inb1; const float* ing1; const float* inbt1;
    const float* inW2; const float* inb2; const float* ing2; const float* inbt2;
    const float* cW1; const float* cb1; const float* cg1; const float* cbt1;
    const float* cW2; const float* cb2; const float* cg2; const float* cbt2;
    const float* ceps; const float* lng; const float* lnb;
    const float* outW; const float* outb;
    const int* ecat;
    unsigned* nep; unsigned* catp;
    float* hA; float* hB; float* dout;
};

// ---------------------------------------------------------------------------
// Fused kernel. Block (b, jg) owns dst rows jg*4..jg*4+3 of item b.
// grid = 512 blocks x 512 threads; LDS 40 KB -> 2 blocks/CU (16 waves/CU).
// lbeg<0: run phase0 (input MLP + nep + catp). Layers [max(lbeg,0), lend).
__global__ __launch_bounds__(512, 4) void k_fused(KArgs a, int lbeg, int lend, int dosync)
{
    __shared__ __align__(16) uint4    sNe4[NCATS * 17];   // 17408 B bf16 ne (padded)
    __shared__ __align__(16) float    sPart[8 * 4 * 128]; // 16 KB agg/GEMM partials
    __shared__ __align__(16) unsigned sCat[256];          // 1 KB: 4 dst cats / src
    __shared__ __align__(16) uint2    sUT[128];           // 1 KB transposed bf16 u
    __shared__ __align__(16) float    sH1[4][128];        // 2 KB
    __shared__ __align__(16) uint2    sH1T[128];          // 1 KB
    __shared__ __align__(16) float    sV[4][128];         // 2 KB   (total 40960 B)

    cg::grid_group grid = cg::this_grid();

    const int t  = threadIdx.x;
    const int b  = blockIdx.x >> 6;
    const int jg = blockIdx.x & 63;
    const int w  = t >> 6, lane = t & 63;
    const uint2* sNe2 = (const uint2*)sNe4;

    // ================= phase 0: input MLP (+ nep, catp) =================
    if (lbeg < 0) {
        // (a) first 8 blocks: normalize emb -> nep (wave w -> row blk*8+w)
        if (blockIdx.x < 8) {
            int r = blockIdx.x * 8 + w;
            float2 em = *(const float2*)(a.emb + r * 128 + 2 * lane);
            float q = em.x * em.x + em.y * em.y;
            #pragma unroll
            for (int m = 32; m; m >>= 1) q += __shfl_xor(q, m);
            float cn = sqrtf(q);
            if (cn == 0.f) cn = 1e-8f;
            float sc = fminf(1.0f, 1.0f / cn);
            a.nep[r * 64 + lane] = pack_bf16(em.x * sc, em.y * sc);
        }
        // (b) b==0 blocks: pack cats for their jg -> catp
        if (b == 0 && t < 256) {
            int4 c = *(const int4*)(a.ecat + t * NN + jg * 4);
            a.catp[jg * 256 + t] = (unsigned)c.x | ((unsigned)c.y << 8) |
                                   ((unsigned)c.z << 16) | ((unsigned)c.w << 24);
        }
        // (c) input MLP for this block's 4 rows -> hA
        {
            int r = t >> 7, d = t & 127;
            int row = b * NN + jg * 4 + r;
            float x0 = a.x[row * 2 + 0], x1 = a.x[row * 2 + 1];
            sV[r][d] = fmaf(x0, a.inW1[d], fmaf(x1, a.inW1[128 + d], a.inb1[d]));
        }
        __syncthreads();
        if (t < 256) {
            float aa = sV[w][lane], cc = sV[w][lane + 64];
            float mean, rs; ln_stats(aa, cc, mean, rs);
            sH1[w][lane]      = fmaxf((aa - mean) * rs * a.ing1[lane]      + a.inbt1[lane],      0.f);
            sH1[w][lane + 64] = fmaxf((cc - mean) * rs * a.ing1[lane + 64] + a.inbt1[lane + 64], 0.f);
        }
        __syncthreads();
        if (t < 256) {
            int dim = t & 127, p = t >> 7;
            ((unsigned*)sH1T)[dim * 2 + p] = pack_bf16(sH1[2 * p][dim], sH1[2 * p + 1][dim]);
        }
        __syncthreads();
        {   // GEMM2 (4 rows x 128), k-split 4
            const int dd = t & 127, ks = t >> 7;
            float a4[4] = {0.f, 0.f, 0.f, 0.f};
            #pragma unroll 8
            for (int k = 0; k < 32; ++k) {
                int kk = ks * 32 + k;
                uint2 ax = sH1T[kk];
                float wv = a.inW2[kk * 128 + dd];
                a4[0] = fmaf(bf_lo(ax.x), wv, a4[0]);
                a4[1] = fmaf(bf_hi(ax.x), wv, a4[1]);
                a4[2] = fmaf(bf_lo(ax.y), wv, a4[2]);
                a4[3] = fmaf(bf_hi(ax.y), wv, a4[3]);
            }
            #pragma unroll
            for (int r = 0; r < 4; ++r) sPart[(ks * 4 + r) * 128 + dd] = a4[r];
        }
        __syncthreads();
        {
            int r = t >> 7, dim = t & 127;
            sV[r][dim] = a.inb2[dim] + sPart[r * 128 + dim] + sPart[(4 + r) * 128 + dim] +
                         sPart[(8 + r) * 128 + dim] + sPart[(12 + r) * 128 + dim];
        }
        __syncthreads();
        if (t < 256) {
            float aa = sV[w][lane], cc = sV[w][lane + 64];
            float mean, rs; ln_stats(aa, cc, mean, rs);
            int grow = b * NN + jg * 4 + w;
            a.hA[grow * HID + lane]      = (aa - mean) * rs * a.ing2[lane]      + a.inbt2[lane];
            a.hA[grow * HID + lane + 64] = (cc - mean) * rs * a.ing2[lane + 64] + a.inbt2[lane + 64];
        }
        if (dosync) grid.sync();
    }

    // ========== stage ne + cats ONCE (persists across all layers) ==========
    {
        const uint4* nep4 = (const uint4*)a.nep;
        for (int idx = t; idx < 1024; idx += 512) {
            int row = idx >> 4, col = idx & 15;
            sNe4[row * 17 + col] = nep4[idx];
        }
        if (t < 256) sCat[t] = a.catp[jg * 256 + t];
    }
    __syncthreads();

    // ================= layers =================
    #pragma unroll 1
    for (int l = (lbeg < 0 ? 0 : lbeg); l < lend; ++l) {
        const float* h_old = (l & 1) ? a.hB : a.hA;
        float*       h_new = (l & 1) ? a.hA : a.hB;
        const float* W1  = a.cW1 + l * HID * HID;
        const float* W2  = a.cW2 + l * HID * HID;
        const float* b1  = a.cb1 + l * HID;
        const float* b2  = a.cb2 + l * HID;
        const float* g1  = a.cg1 + l * HID;
        const float* bt1 = a.cbt1 + l * HID;
        const float* g2  = a.cg2 + l * HID;
        const float* bt2 = a.cbt2 + l * HID;
        const float* lg  = a.lng + l * HID;
        const float* lb  = a.lnb + l * HID;
        const float* hb  = h_old + (size_t)b * NN * HID;
        const int isLast = (l == 3);

        // ---- aggregation: dims [dg*4), srcs [ig*16,+16), 4 dst in regs ----
        // half-wave shares one src i -> sNe read is uniform+consecutive.
        const int dg = t & 31;
        const int ig = t >> 5;
        float acc[4][4];
        #pragma unroll
        for (int k = 0; k < 4; ++k)
            #pragma unroll
            for (int d = 0; d < 4; ++d) acc[k][d] = 0.f;

        #pragma unroll
        for (int n = 0; n < 16; ++n) {
            int i = ig * 16 + n;
            float4 hv = *(const float4*)(hb + i * HID + dg * 4);
            unsigned c4 = sCat[i];
            #pragma unroll
            for (int k = 0; k < 4; ++k) {
                unsigned c = (c4 >> (8 * k)) & 255u;
                uint2 nv = sNe2[c * 34 + dg];
                acc[k][0] += fmaxf(hv.x + bf_lo(nv.x), 0.f);
                acc[k][1] += fmaxf(hv.y + bf_hi(nv.x), 0.f);
                acc[k][2] += fmaxf(hv.z + bf_lo(nv.y), 0.f);
                acc[k][3] += fmaxf(hv.w + bf_hi(nv.y), 0.f);
            }
        }
        // merge the wave's two src subgroups (lane ^ 32)
        #pragma unroll
        for (int k = 0; k < 4; ++k)
            #pragma unroll
            for (int d = 0; d < 4; ++d)
                acc[k][d] += __shfl_xor(acc[k][d], 32);
        // half-wave 0 writes rows 0,1; half-wave 1 writes rows 2,3
        {
            int hw = (t >> 5) & 1;
            int r0 = 2 * hw;
            *(float4*)&sPart[(w * 4 + r0)     * 128 + dg * 4] =
                make_float4(acc[r0][0], acc[r0][1], acc[r0][2], acc[r0][3]);
            *(float4*)&sPart[(w * 4 + r0 + 1) * 128 + dg * 4] =
                make_float4(acc[r0+1][0], acc[r0+1][1], acc[r0+1][2], acc[r0+1][3]);
        }
        __syncthreads();

        // ---- combine 8 partials, u = (1+eps)*h + agg -> transposed bf16 ----
        if (t < 256) {
            int dim = t & 127, p = t >> 7;
            const float eps1 = 1.0f + a.ceps[l];
            int r0 = 2 * p, r1 = 2 * p + 1;
            float u0 = eps1 * hb[(jg * 4 + r0) * HID + dim];
            float u1 = eps1 * hb[(jg * 4 + r1) * HID + dim];
            #pragma unroll
            for (int pg = 0; pg < 8; ++pg) {
                u0 += sPart[(pg * 4 + r0) * 128 + dim];
                u1 += sPart[(pg * 4 + r1) * 128 + dim];
            }
            ((unsigned*)sUT)[dim * 2 + p] = pack_bf16(u0, u1);
        }
        __syncthreads();

        // ---- GEMM1 ----
        {
            const int dd = t & 127, ks = t >> 7;
            float a4[4] = {0.f, 0.f, 0.f, 0.f};
            #pragma unroll 8
            for (int k = 0; k < 32; ++k) {
                int kk = ks * 32 + k;
                uint2 ax = sUT[kk];
                float wv = W1[kk * 128 + dd];
                a4[0] = fmaf(bf_lo(ax.x), wv, a4[0]);
                a4[1] = fmaf(bf_hi(ax.x), wv, a4[1]);
                a4[2] = fmaf(bf_lo(ax.y), wv, a4[2]);
                a4[3] = fmaf(bf_hi(ax.y), wv, a4[3]);
            }
            #pragma unroll
            for (int r = 0; r < 4; ++r) sPart[(ks * 4 + r) * 128 + dd] = a4[r];
        }
        __syncthreads();
        {
            int r = t >> 7, dim = t & 127;
            sV[r][dim] = b1[dim] + sPart[r * 128 + dim] + sPart[(4 + r) * 128 + dim] +
                         sPart[(8 + r) * 128 + dim] + sPart[(12 + r) * 128 + dim];
        }
        __syncthreads();

        // ---- LN1 + relu ----
        if (t < 256) {
            float aa = sV[w][lane], cc = sV[w][lane + 64];
            float mean, rs; ln_stats(aa, cc, mean, rs);
            sH1[w][lane]      = fmaxf((aa - mean) * rs * g1[lane]      + bt1[lane],      0.f);
            sH1[w][lane + 64] = fmaxf((cc - mean) * rs * g1[lane + 64] + bt1[lane + 64], 0.f);
        }
        __syncthreads();
        if (t < 256) {
            int dim = t & 127, p = t >> 7;
            ((unsigned*)sH1T)[dim * 2 + p] = pack_bf16(sH1[2 * p][dim], sH1[2 * p + 1][dim]);
        }
        __syncthreads();

        // ---- GEMM2 ----
        {
            const int dd = t & 127, ks = t >> 7;
            float a4[4] = {0.f, 0.f, 0.f, 0.f};
            #pragma unroll 8
            for (int k = 0; k < 32; ++k) {
                int kk = ks * 32 + k;
                uint2 ax = sH1T[kk];
                float wv = W2[kk * 128 + dd];
                a4[0] = fmaf(bf_lo(ax.x), wv, a4[0]);
                a4[1] = fmaf(bf_hi(ax.x), wv, a4[1]);
                a4[2] = fmaf(bf_lo(ax.y), wv, a4[2]);
                a4[3] = fmaf(bf_hi(ax.y), wv, a4[3]);
            }
            #pragma unroll
            for (int r = 0; r < 4; ++r) sPart[(ks * 4 + r) * 128 + dd] = a4[r];
        }
        __syncthreads();
        {
            int r = t >> 7, dim = t & 127;
            sV[r][dim] = b2[dim] + sPart[r * 128 + dim] + sPart[(4 + r) * 128 + dim] +
                         sPart[(8 + r) * 128 + dim] + sPart[(12 + r) * 128 + dim];
        }
        __syncthreads();

        // ---- LN2 -> LN3 + relu + residual -> h_new / output ----
        if (t < 256) {
            float aa = sV[w][lane], cc = sV[w][lane + 64];
            float mean, rs; ln_stats(aa, cc, mean, rs);
            float y1 = (aa - mean) * rs * g2[lane]      + bt2[lane];
            float y2 = (cc - mean) * rs * g2[lane + 64] + bt2[lane + 64];

            float mean3, rs3; ln_stats(y1, y2, mean3, rs3);
            int row = jg * 4 + w;
            int grow = b * NN + row;
            float ho1 = hb[row * HID + lane], ho2 = hb[row * HID + lane + 64];
            float z1 = fmaxf((y1 - mean3) * rs3 * lg[lane]      + lb[lane],      0.f) + ho1;
            float z2 = fmaxf((y2 - mean3) * rs3 * lg[lane + 64] + lb[lane + 64], 0.f) + ho2;

            if (!isLast) {
                h_new[(size_t)grow * HID + lane]      = z1;
                h_new[(size_t)grow * HID + lane + 64] = z2;
            } else {
                #pragma unroll
                for (int ccx = 0; ccx < 3; ++ccx) {
                    float p = z1 * a.outW[lane * 3 + ccx] + z2 * a.outW[(lane + 64) * 3 + ccx];
                    #pragma unroll
                    for (int m = 32; m; m >>= 1) p += __shfl_xor(p, m);
                    if (lane == 0) a.dout[grow * 3 + ccx] = p + a.outb[ccx];
                }
            }
        }
        if (dosync && l < 3) grid.sync();
    }
}

// ---------------------------------------------------------------------------
extern "C" void kernel_launch(void* const* d_in, const int* in_sizes, int n_in,
                              void* d_out, int out_size, void* d_ws, size_t ws_size,
                              hipStream_t stream) {
    float* ws = (float*)d_ws;
    KArgs ka;
    ka.x     = (const float*)d_in[0];
    ka.emb   = (const float*)d_in[1];
    ka.inW1  = (const float*)d_in[2];
    ka.inb1  = (const float*)d_in[3];
    ka.ing1  = (const float*)d_in[4];
    ka.inbt1 = (const float*)d_in[5];
    ka.inW2  = (const float*)d_in[6];
    ka.inb2  = (const float*)d_in[7];
    ka.ing2  = (const float*)d_in[8];
    ka.inbt2 = (const float*)d_in[9];
    ka.cW1   = (const float*)d_in[10];
    ka.cb1   = (const float*)d_in[11];
    ka.cg1   = (const float*)d_in[12];
    ka.cbt1  = (const float*)d_in[13];
    ka.cW2   = (const float*)d_in[14];
    ka.cb2   = (const float*)d_in[15];
    ka.cg2   = (const float*)d_in[16];
    ka.cbt2  = (const float*)d_in[17];
    ka.ceps  = (const float*)d_in[18];
    ka.lng   = (const float*)d_in[19];
    ka.lnb   = (const float*)d_in[20];
    ka.outW  = (const float*)d_in[21];
    ka.outb  = (const float*)d_in[22];
    ka.ecat  = (const int*)d_in[25];
    ka.nep   = (unsigned*)ws;                   // 4096 u32
    ka.catp  = (unsigned*)(ws + 4096);          // 16384 u32
    ka.hA    = ws + 4096 + 16384;
    ka.hB    = ka.hA + BB * NN * HID;
    ka.dout  = (float*)d_out;

    // capture-safe host-side decision: need 2 blocks/CU for coop grid 512
    int nb = 0;
    hipError_t oe = hipOccupancyMaxActiveBlocksPerMultiprocessor(&nb, k_fused, 512, 0);
    bool coop_ok = (oe == hipSuccess && nb >= 2);

    if (coop_ok) {
        int lbeg = -1, lend = 4, dosync = 1;
        void* kp[] = { (void*)&ka, (void*)&lbeg, (void*)&lend, (void*)&dosync };
        hipError_t le = hipLaunchCooperativeKernel((const void*)k_fused,
                                                   dim3(512), dim3(512), kp, 0, stream);
        if (le == hipSuccess) return;
    }
    // fallback: 5 plain launches (kernel boundaries provide the sync)
    k_fused<<<512, 512, 0, stream>>>(ka, -1, 0, 0);
    k_fused<<<512, 512, 0, stream>>>(ka, 0, 1, 0);
    k_fused<<<512, 512, 0, stream>>>(ka, 1, 2, 0);
    k_fused<<<512, 512, 0, stream>>>(ka, 2, 3, 0);
    k_fused<<<512, 512, 0, stream>>>(ka, 3, 4, 0);
}

// Round 7
// 121.629 us; speedup vs baseline: 2.4941x; 2.4941x over previous
//
#include <hip/hip_runtime.h>

#define HID 128
#define NN  256
#define BB  8
#define NCATS 64

// ---------------------------------------------------------------------------
// bf16 pack/unpack (RNE rounding on pack)
__device__ inline unsigned pack_bf16(float lo, float hi) {
    unsigned ul = __float_as_uint(lo);
    unsigned uh = __float_as_uint(hi);
    ul = (ul + 0x7fffu + ((ul >> 16) & 1u)) >> 16;
    uh = (uh + 0x7fffu + ((uh >> 16) & 1u)) & 0xffff0000u;
    return ul | uh;
}
__device__ inline float bf_lo(unsigned v) { return __uint_as_float(v << 16); }
__device__ inline float bf_hi(unsigned v) { return __uint_as_float(v & 0xffff0000u); }

// Wave-per-row LN reduction (row split as a=dim[lane], c=dim[lane+64]).
__device__ inline void ln_stats(float a, float c, float& mean, float& rs) {
    float s = a + c;
    float q = a * a + c * c;
    #pragma unroll
    for (int m = 32; m; m >>= 1) {
        s += __shfl_xor(s, m);
        q += __shfl_xor(q, m);
    }
    mean = s * (1.0f / 128.0f);
    float var = q * (1.0f / 128.0f) - mean * mean;
    rs = rsqrtf(var + 1e-5f);
}

// ---------------------------------------------------------------------------
// Setup kernel:
//   blocks [0,256):   input MLP, 8 rows each  -> h0
//   blocks [256,264): normalize emb -> nep (bf16-packed pairs)
//   blocks [264,328): pack edge_cat: catp[jg*256+i] = cats of (i, jg*4..+3)
__global__ __launch_bounds__(512) void k_setup(
    const float* __restrict__ x, const float* __restrict__ emb,
    const float* __restrict__ inW1, const float* __restrict__ inb1,
    const float* __restrict__ ing1, const float* __restrict__ inbt1,
    const float* __restrict__ inW2, const float* __restrict__ inb2,
    const float* __restrict__ ing2, const float* __restrict__ inbt2,
    const int* __restrict__ ecat,
    unsigned* __restrict__ nep, unsigned* __restrict__ catp, float* __restrict__ h0)
{
    __shared__ __align__(16) float sV[8][128];
    __shared__ __align__(16) float sH1[8][128];
    __shared__ __align__(16) float sA[4][8][128];
    __shared__ __align__(16) uint4 sH1T[128];

    const int blk = blockIdx.x;
    const int t = threadIdx.x;
    const int w = t >> 6, lane = t & 63;

    if (blk < 256) {
        const int row0 = blk * 8;
        for (int item = t; item < 1024; item += 512) {
            int r = item >> 7, d2 = item & 127;
            int row = row0 + r;
            float x0 = x[row * 2 + 0], x1 = x[row * 2 + 1];
            sV[r][d2] = fmaf(x0, inW1[d2], fmaf(x1, inW1[128 + d2], inb1[d2]));
        }
        __syncthreads();
        {
            float a = sV[w][lane], c = sV[w][lane + 64];
            float mean, rs; ln_stats(a, c, mean, rs);
            sH1[w][lane]      = fmaxf((a - mean) * rs * ing1[lane]      + inbt1[lane],      0.f);
            sH1[w][lane + 64] = fmaxf((c - mean) * rs * ing1[lane + 64] + inbt1[lane + 64], 0.f);
        }
        __syncthreads();
        {
            int kd = t & 127, wr = t >> 7;
            ((unsigned*)sH1T)[kd * 4 + wr] = pack_bf16(sH1[2 * wr][kd], sH1[2 * wr + 1][kd]);
        }
        __syncthreads();
        {
            const int dd = t & 127, ks = t >> 7;
            float a8[8] = {0.f,0.f,0.f,0.f,0.f,0.f,0.f,0.f};
            #pragma unroll 8
            for (int k = 0; k < 32; ++k) {
                int kk = ks * 32 + k;
                uint4 a = sH1T[kk];
                float wv = inW2[kk * 128 + dd];
                a8[0] = fmaf(bf_lo(a.x), wv, a8[0]);
                a8[1] = fmaf(bf_hi(a.x), wv, a8[1]);
                a8[2] = fmaf(bf_lo(a.y), wv, a8[2]);
                a8[3] = fmaf(bf_hi(a.y), wv, a8[3]);
                a8[4] = fmaf(bf_lo(a.z), wv, a8[4]);
                a8[5] = fmaf(bf_hi(a.z), wv, a8[5]);
                a8[6] = fmaf(bf_lo(a.w), wv, a8[6]);
                a8[7] = fmaf(bf_hi(a.w), wv, a8[7]);
            }
            #pragma unroll
            for (int r = 0; r < 8; ++r) sA[ks][r][dd] = a8[r];
        }
        __syncthreads();
        for (int item = t; item < 1024; item += 512) {
            int r = item >> 7, d2 = item & 127;
            sV[r][d2] = inb2[d2] + sA[0][r][d2] + sA[1][r][d2] + sA[2][r][d2] + sA[3][r][d2];
        }
        __syncthreads();
        {
            float a = sV[w][lane], c = sV[w][lane + 64];
            float mean, rs; ln_stats(a, c, mean, rs);
            int row = row0 + w;
            h0[row * HID + lane]      = (a - mean) * rs * ing2[lane]      + inbt2[lane];
            h0[row * HID + lane + 64] = (c - mean) * rs * ing2[lane + 64] + inbt2[lane + 64];
        }
    } else if (blk < 264) {
        int r = (blk - 256) * 8 + w;
        float2 em = *(const float2*)(emb + r * 128 + 2 * lane);
        float q = em.x * em.x + em.y * em.y;
        #pragma unroll
        for (int m = 32; m; m >>= 1) q += __shfl_xor(q, m);
        float cn = sqrtf(q);
        if (cn == 0.f) cn = 1e-8f;
        float sc = fminf(1.0f, 1.0f / cn);
        nep[r * 64 + lane] = pack_bf16(em.x * sc, em.y * sc);
    } else {
        int jg = blk - 264;
        if (t < 256) {
            int4 c = *(const int4*)(ecat + t * NN + jg * 4);
            catp[jg * 256 + t] = (unsigned)c.x | ((unsigned)c.y << 8) |
                                 ((unsigned)c.z << 16) | ((unsigned)c.w << 24);
        }
    }
}

// ---------------------------------------------------------------------------
// One GINE layer. Block (b, jg) owns dst rows jg*4..jg*4+3 of item b.
// grid = 512 x 512 threads. LDS ~41 KB. Plain launch_bounds (no forced
// VGPR squeeze -- R2/R6 lesson: min-waves hints cause catastrophic spill).
__global__ __launch_bounds__(512) void k_layer(
    const float* __restrict__ h_old, float* __restrict__ h_new,
    const uint4* __restrict__ nep4, const unsigned* __restrict__ catp,
    const float* __restrict__ W1, const float* __restrict__ b1,
    const float* __restrict__ g1, const float* __restrict__ bt1,
    const float* __restrict__ W2, const float* __restrict__ b2,
    const float* __restrict__ g2, const float* __restrict__ bt2,
    const float* __restrict__ epsp,
    const float* __restrict__ lng, const float* __restrict__ lnb,
    const float* __restrict__ outW, const float* __restrict__ outb,
    float* __restrict__ dout, int isLast)
{
    __shared__ __align__(16) uint4    sNe4[NCATS * 17];   // 17408 B bf16 ne (padded)
    __shared__ __align__(16) float    sPart[8 * 4 * 128]; // 16 KB agg/GEMM partials
    __shared__ __align__(16) unsigned sCat[256];          // 1 KB
    __shared__ __align__(16) uint2    sUT[128];           // 1 KB
    __shared__ __align__(16) float    sH1[4][128];        // 2 KB
    __shared__ __align__(16) uint2    sH1T[128];          // 1 KB
    __shared__ __align__(16) float    sV[4][128];         // 2 KB

    const int t  = threadIdx.x;
    const int b  = blockIdx.x >> 6;
    const int jg = blockIdx.x & 63;
    const int w  = t >> 6, lane = t & 63;
    const float* hb = h_old + (size_t)b * NN * HID;
    const uint2* sNe2 = (const uint2*)sNe4;

    // stage bf16 ne (padded) + this block's packed cats
    for (int idx = t; idx < 1024; idx += 512) {
        int row = idx >> 4, col = idx & 15;
        sNe4[row * 17 + col] = nep4[idx];
    }
    if (t < 256) sCat[t] = catp[jg * 256 + t];
    __syncthreads();

    // ---- aggregation: dims [dg*4,+4), srcs [ig*16,+16), 4 dst in regs ----
    const int dg = t & 31;
    const int ig = t >> 5;
    float acc[4][4];
    #pragma unroll
    for (int k = 0; k < 4; ++k)
        #pragma unroll
        for (int d = 0; d < 4; ++d) acc[k][d] = 0.f;

    #pragma unroll
    for (int n = 0; n < 16; ++n) {
        int i = ig * 16 + n;
        float4 hv = *(const float4*)(hb + i * HID + dg * 4);
        unsigned c4 = sCat[i];
        #pragma unroll
        for (int k = 0; k < 4; ++k) {
            unsigned c = (c4 >> (8 * k)) & 255u;
            uint2 nv = sNe2[c * 34 + dg];
            acc[k][0] += fmaxf(hv.x + bf_lo(nv.x), 0.f);
            acc[k][1] += fmaxf(hv.y + bf_hi(nv.x), 0.f);
            acc[k][2] += fmaxf(hv.z + bf_lo(nv.y), 0.f);
            acc[k][3] += fmaxf(hv.w + bf_hi(nv.y), 0.f);
        }
    }
    // merge the wave's two src subgroups (lane ^ 32)
    #pragma unroll
    for (int k = 0; k < 4; ++k)
        #pragma unroll
        for (int d = 0; d < 4; ++d)
            acc[k][d] += __shfl_xor(acc[k][d], 32);
    // half-wave 0 writes rows 0,1; half-wave 1 writes rows 2,3
    {
        int hw = (t >> 5) & 1;
        int r0 = 2 * hw;
        *(float4*)&sPart[(w * 4 + r0)     * 128 + dg * 4] =
            make_float4(acc[r0][0], acc[r0][1], acc[r0][2], acc[r0][3]);
        *(float4*)&sPart[(w * 4 + r0 + 1) * 128 + dg * 4] =
            make_float4(acc[r0+1][0], acc[r0+1][1], acc[r0+1][2], acc[r0+1][3]);
    }
    __syncthreads();

    // ---- combine 8 partials, u = (1+eps)*h + agg -> transposed bf16 ----
    if (t < 256) {
        int dim = t & 127, p = t >> 7;
        const float eps1 = 1.0f + epsp[0];
        int r0 = 2 * p, r1 = 2 * p + 1;
        float u0 = eps1 * hb[(jg * 4 + r0) * HID + dim];
        float u1 = eps1 * hb[(jg * 4 + r1) * HID + dim];
        #pragma unroll
        for (int pg = 0; pg < 8; ++pg) {
            u0 += sPart[(pg * 4 + r0) * 128 + dim];
            u1 += sPart[(pg * 4 + r1) * 128 + dim];
        }
        ((unsigned*)sUT)[dim * 2 + p] = pack_bf16(u0, u1);
    }
    __syncthreads();

    // ---- GEMM1: v = u @ W1 ----
    {
        const int dd = t & 127, ks = t >> 7;
        float a4[4] = {0.f, 0.f, 0.f, 0.f};
        #pragma unroll 8
        for (int k = 0; k < 32; ++k) {
            int kk = ks * 32 + k;
            uint2 ax = sUT[kk];
            float wv = W1[kk * 128 + dd];
            a4[0] = fmaf(bf_lo(ax.x), wv, a4[0]);
            a4[1] = fmaf(bf_hi(ax.x), wv, a4[1]);
            a4[2] = fmaf(bf_lo(ax.y), wv, a4[2]);
            a4[3] = fmaf(bf_hi(ax.y), wv, a4[3]);
        }
        #pragma unroll
        for (int r = 0; r < 4; ++r) sPart[(ks * 4 + r) * 128 + dd] = a4[r];
    }
    __syncthreads();
    {
        int r = t >> 7, dim = t & 127;
        sV[r][dim] = b1[dim] + sPart[r * 128 + dim] + sPart[(4 + r) * 128 + dim] +
                     sPart[(8 + r) * 128 + dim] + sPart[(12 + r) * 128 + dim];
    }
    __syncthreads();

    // ---- LN1 + relu ----
    if (t < 256) {
        float aa = sV[w][lane], cc = sV[w][lane + 64];
        float mean, rs; ln_stats(aa, cc, mean, rs);
        sH1[w][lane]      = fmaxf((aa - mean) * rs * g1[lane]      + bt1[lane],      0.f);
        sH1[w][lane + 64] = fmaxf((cc - mean) * rs * g1[lane + 64] + bt1[lane + 64], 0.f);
    }
    __syncthreads();
    if (t < 256) {
        int dim = t & 127, p = t >> 7;
        ((unsigned*)sH1T)[dim * 2 + p] = pack_bf16(sH1[2 * p][dim], sH1[2 * p + 1][dim]);
    }
    __syncthreads();

    // ---- GEMM2: v = h1 @ W2 ----
    {
        const int dd = t & 127, ks = t >> 7;
        float a4[4] = {0.f, 0.f, 0.f, 0.f};
        #pragma unroll 8
        for (int k = 0; k < 32; ++k) {
            int kk = ks * 32 + k;
            uint2 ax = sH1T[kk];
            float wv = W2[kk * 128 + dd];
            a4[0] = fmaf(bf_lo(ax.x), wv, a4[0]);
            a4[1] = fmaf(bf_hi(ax.x), wv, a4[1]);
            a4[2] = fmaf(bf_lo(ax.y), wv, a4[2]);
            a4[3] = fmaf(bf_hi(ax.y), wv, a4[3]);
        }
        #pragma unroll
        for (int r = 0; r < 4; ++r) sPart[(ks * 4 + r) * 128 + dd] = a4[r];
    }
    __syncthreads();
    {
        int r = t >> 7, dim = t & 127;
        sV[r][dim] = b2[dim] + sPart[r * 128 + dim] + sPart[(4 + r) * 128 + dim] +
                     sPart[(8 + r) * 128 + dim] + sPart[(12 + r) * 128 + dim];
    }
    __syncthreads();

    // ---- LN2 -> LN3 + relu + residual -> h_new / output ----
    if (t < 256) {
        float aa = sV[w][lane], cc = sV[w][lane + 64];
        float mean, rs; ln_stats(aa, cc, mean, rs);
        float y1 = (aa - mean) * rs * g2[lane]      + bt2[lane];
        float y2 = (cc - mean) * rs * g2[lane + 64] + bt2[lane + 64];

        float mean3, rs3; ln_stats(y1, y2, mean3, rs3);
        int row = jg * 4 + w;
        int grow = b * NN + row;
        float ho1 = hb[row * HID + lane], ho2 = hb[row * HID + lane + 64];
        float z1 = fmaxf((y1 - mean3) * rs3 * lng[lane]      + lnb[lane],      0.f) + ho1;
        float z2 = fmaxf((y2 - mean3) * rs3 * lng[lane + 64] + lnb[lane + 64], 0.f) + ho2;

        if (!isLast) {
            h_new[(size_t)grow * HID + lane]      = z1;
            h_new[(size_t)grow * HID + lane + 64] = z2;
        } else {
            #pragma unroll
            for (int ccx = 0; ccx < 3; ++ccx) {
                float p = z1 * outW[lane * 3 + ccx] + z2 * outW[(lane + 64) * 3 + ccx];
                #pragma unroll
                for (int m = 32; m; m >>= 1) p += __shfl_xor(p, m);
                if (lane == 0) dout[grow * 3 + ccx] = p + outb[ccx];
            }
        }
    }
}

// ---------------------------------------------------------------------------
extern "C" void kernel_launch(void* const* d_in, const int* in_sizes, int n_in,
                              void* d_out, int out_size, void* d_ws, size_t ws_size,
                              hipStream_t stream) {
    const float* x     = (const float*)d_in[0];
    const float* emb   = (const float*)d_in[1];
    const float* inW1  = (const float*)d_in[2];
    const float* inb1  = (const float*)d_in[3];
    const float* ing1  = (const float*)d_in[4];
    const float* inbt1 = (const float*)d_in[5];
    const float* inW2  = (const float*)d_in[6];
    const float* inb2  = (const float*)d_in[7];
    const float* ing2  = (const float*)d_in[8];
    const float* inbt2 = (const float*)d_in[9];
    const float* cW1   = (const float*)d_in[10];
    const float* cb1   = (const float*)d_in[11];
    const float* cg1   = (const float*)d_in[12];
    const float* cbt1  = (const float*)d_in[13];
    const float* cW2   = (const float*)d_in[14];
    const float* cb2   = (const float*)d_in[15];
    const float* cg2   = (const float*)d_in[16];
    const float* cbt2  = (const float*)d_in[17];
    const float* ceps  = (const float*)d_in[18];
    const float* lng   = (const float*)d_in[19];
    const float* lnb   = (const float*)d_in[20];
    const float* outW  = (const float*)d_in[21];
    const float* outb  = (const float*)d_in[22];
    const int*   ecat  = (const int*)d_in[25];

    float* ws      = (float*)d_ws;
    unsigned* nep  = (unsigned*)ws;             // 4096 u32 (16 KB bf16 ne)
    unsigned* catp = (unsigned*)(ws + 4096);    // 16384 u32
    float* hA   = ws + 4096 + 16384;            // B*N*HID
    float* hB   = hA + BB * NN * HID;
    float* out  = (float*)d_out;

    k_setup<<<328, 512, 0, stream>>>(x, emb, inW1, inb1, ing1, inbt1,
                                     inW2, inb2, ing2, inbt2, ecat, nep, catp, hA);

    for (int l = 0; l < 4; ++l) {
        const float* ho = (l & 1) ? hB : hA;
        float*       hn = (l & 1) ? hA : hB;
        k_layer<<<512, 512, 0, stream>>>(
            ho, hn, (const uint4*)nep, catp,
            cW1 + l * HID * HID, cb1 + l * HID, cg1 + l * HID, cbt1 + l * HID,
            cW2 + l * HID * HID, cb2 + l * HID, cg2 + l * HID, cbt2 + l * HID,
            ceps + l, lng + l * HID, lnb + l * HID,
            outW, outb, out, (l == 3) ? 1 : 0);
    }
}

// Round 8
// 91.553 us; speedup vs baseline: 3.3134x; 1.3285x over previous
//
#include <hip/hip_runtime.h>

#define HID 128
#define NN  256
#define BB  8
#define NCATS 64

// ---------------------------------------------------------------------------
// bf16 pack/unpack (RNE rounding on pack)
__device__ inline unsigned pack_bf16(float lo, float hi) {
    unsigned ul = __float_as_uint(lo);
    unsigned uh = __float_as_uint(hi);
    ul = (ul + 0x7fffu + ((ul >> 16) & 1u)) >> 16;
    uh = (uh + 0x7fffu + ((uh >> 16) & 1u)) & 0xffff0000u;
    return ul | uh;
}
__device__ inline float bf_lo(unsigned v) { return __uint_as_float(v << 16); }
__device__ inline float bf_hi(unsigned v) { return __uint_as_float(v & 0xffff0000u); }

// Wave-per-row LN reduction (row split as a=dim[lane], c=dim[lane+64]).
__device__ inline void ln_stats(float a, float c, float& mean, float& rs) {
    float s = a + c;
    float q = a * a + c * c;
    #pragma unroll
    for (int m = 32; m; m >>= 1) {
        s += __shfl_xor(s, m);
        q += __shfl_xor(q, m);
    }
    mean = s * (1.0f / 128.0f);
    float var = q * (1.0f / 128.0f) - mean * mean;
    rs = rsqrtf(var + 1e-5f);
}

// ---------------------------------------------------------------------------
// Setup kernel:
//   blocks [0,256):   input MLP, 8 rows each  -> h0
//   blocks [256,264): normalize emb -> nep (bf16-packed pairs)
//   blocks [264,296): pack edge_cat: catp[jb*256+i] = uint2 of cats (i, jb*8..+7)
__global__ __launch_bounds__(512) void k_setup(
    const float* __restrict__ x, const float* __restrict__ emb,
    const float* __restrict__ inW1, const float* __restrict__ inb1,
    const float* __restrict__ ing1, const float* __restrict__ inbt1,
    const float* __restrict__ inW2, const float* __restrict__ inb2,
    const float* __restrict__ ing2, const float* __restrict__ inbt2,
    const int* __restrict__ ecat,
    unsigned* __restrict__ nep, uint2* __restrict__ catp, float* __restrict__ h0)
{
    __shared__ __align__(16) float sV[8][128];
    __shared__ __align__(16) float sH1[8][128];
    __shared__ __align__(16) float sA[4][8][128];
    __shared__ __align__(16) uint4 sH1T[128];

    const int blk = blockIdx.x;
    const int t = threadIdx.x;
    const int w = t >> 6, lane = t & 63;

    if (blk < 256) {
        const int row0 = blk * 8;
        for (int item = t; item < 1024; item += 512) {
            int r = item >> 7, d2 = item & 127;
            int row = row0 + r;
            float x0 = x[row * 2 + 0], x1 = x[row * 2 + 1];
            sV[r][d2] = fmaf(x0, inW1[d2], fmaf(x1, inW1[128 + d2], inb1[d2]));
        }
        __syncthreads();
        {
            float a = sV[w][lane], c = sV[w][lane + 64];
            float mean, rs; ln_stats(a, c, mean, rs);
            sH1[w][lane]      = fmaxf((a - mean) * rs * ing1[lane]      + inbt1[lane],      0.f);
            sH1[w][lane + 64] = fmaxf((c - mean) * rs * ing1[lane + 64] + inbt1[lane + 64], 0.f);
        }
        __syncthreads();
        {
            int kd = t & 127, wr = t >> 7;
            ((unsigned*)sH1T)[kd * 4 + wr] = pack_bf16(sH1[2 * wr][kd], sH1[2 * wr + 1][kd]);
        }
        __syncthreads();
        {
            const int dd = t & 127, ks = t >> 7;
            float a8[8] = {0.f,0.f,0.f,0.f,0.f,0.f,0.f,0.f};
            #pragma unroll 8
            for (int k = 0; k < 32; ++k) {
                int kk = ks * 32 + k;
                uint4 a = sH1T[kk];
                float wv = inW2[kk * 128 + dd];
                a8[0] = fmaf(bf_lo(a.x), wv, a8[0]);
                a8[1] = fmaf(bf_hi(a.x), wv, a8[1]);
                a8[2] = fmaf(bf_lo(a.y), wv, a8[2]);
                a8[3] = fmaf(bf_hi(a.y), wv, a8[3]);
                a8[4] = fmaf(bf_lo(a.z), wv, a8[4]);
                a8[5] = fmaf(bf_hi(a.z), wv, a8[5]);
                a8[6] = fmaf(bf_lo(a.w), wv, a8[6]);
                a8[7] = fmaf(bf_hi(a.w), wv, a8[7]);
            }
            #pragma unroll
            for (int r = 0; r < 8; ++r) sA[ks][r][dd] = a8[r];
        }
        __syncthreads();
        for (int item = t; item < 1024; item += 512) {
            int r = item >> 7, d2 = item & 127;
            sV[r][d2] = inb2[d2] + sA[0][r][d2] + sA[1][r][d2] + sA[2][r][d2] + sA[3][r][d2];
        }
        __syncthreads();
        {
            float a = sV[w][lane], c = sV[w][lane + 64];
            float mean, rs; ln_stats(a, c, mean, rs);
            int row = row0 + w;
            h0[row * HID + lane]      = (a - mean) * rs * ing2[lane]      + inbt2[lane];
            h0[row * HID + lane + 64] = (c - mean) * rs * ing2[lane + 64] + inbt2[lane + 64];
        }
    } else if (blk < 264) {
        int r = (blk - 256) * 8 + w;
        float2 em = *(const float2*)(emb + r * 128 + 2 * lane);
        float q = em.x * em.x + em.y * em.y;
        #pragma unroll
        for (int m = 32; m; m >>= 1) q += __shfl_xor(q, m);
        float cn = sqrtf(q);
        if (cn == 0.f) cn = 1e-8f;
        float sc = fminf(1.0f, 1.0f / cn);
        nep[r * 64 + lane] = pack_bf16(em.x * sc, em.y * sc);
    } else {
        int jb = blk - 264;
        if (t < 256) {
            const int* p = ecat + t * NN + jb * 8;
            int4 c0 = *(const int4*)p;
            int4 c1 = *(const int4*)(p + 4);
            unsigned lo = (unsigned)c0.x | ((unsigned)c0.y << 8) |
                          ((unsigned)c0.z << 16) | ((unsigned)c0.w << 24);
            unsigned hi = (unsigned)c1.x | ((unsigned)c1.y << 8) |
                          ((unsigned)c1.z << 16) | ((unsigned)c1.w << 24);
            catp[jb * 256 + t] = make_uint2(lo, hi);
        }
    }
}

// ---------------------------------------------------------------------------
// One GINE layer. Block (b, jb) owns dst rows jb*8..jb*8+7 of item b.
// grid = 256 x 512 threads, 1 block/CU (8 waves = 2/SIMD -> VGPR-insensitive).
// 8 barriers; every phase uses all 512 threads.
__global__ __launch_bounds__(512) void k_layer(
    const float* __restrict__ h_old, float* __restrict__ h_new,
    const uint4* __restrict__ nep4, const uint2* __restrict__ catp,
    const float* __restrict__ W1, const float* __restrict__ b1,
    const float* __restrict__ g1, const float* __restrict__ bt1,
    const float* __restrict__ W2, const float* __restrict__ b2,
    const float* __restrict__ g2, const float* __restrict__ bt2,
    const float* __restrict__ epsp,
    const float* __restrict__ lng, const float* __restrict__ lnb,
    const float* __restrict__ outW, const float* __restrict__ outb,
    float* __restrict__ dout, int isLast)
{
    __shared__ __align__(16) uint4 sNe4[NCATS * 17];   // 17408 B bf16 ne (padded)
    __shared__ __align__(16) float sPart[8 * 8 * 128]; // 32 KB agg partials / 16 KB GEMM
    __shared__ __align__(16) uint2 sCat[256];          // 2 KB (8 dst cats per src)
    __shared__ __align__(16) uint4 sUT[128];           // 2 KB transposed bf16 u (8 rows)
    __shared__ __align__(16) float sH1[8][128];        // 4 KB
    __shared__ __align__(16) uint4 sH1T[128];          // 2 KB

    const int t  = threadIdx.x;
    const int b  = blockIdx.x >> 5;
    const int jb = blockIdx.x & 31;
    const int w  = t >> 6, lane = t & 63;
    const float* hb = h_old + (size_t)b * NN * HID;
    const uint2* sNe2 = (const uint2*)sNe4;

    // ---- stage bf16 ne (padded rows) + this block's packed cats ----
    for (int idx = t; idx < 1024; idx += 512) {
        int row = idx >> 4, col = idx & 15;
        sNe4[row * 17 + col] = nep4[idx];
    }
    if (t < 256) sCat[t] = catp[jb * 256 + t];
    __syncthreads();

    // ---- aggregation: thread = (4 dims dg, 16 srcs ig); 8 dst rows in regs ----
    const int dg = t & 31;
    const int ig = t >> 5;
    float acc[8][4];
    #pragma unroll
    for (int k = 0; k < 8; ++k)
        #pragma unroll
        for (int d = 0; d < 4; ++d) acc[k][d] = 0.f;

    #pragma unroll
    for (int n = 0; n < 16; ++n) {
        int i = ig * 16 + n;
        float4 hv = *(const float4*)(hb + i * HID + dg * 4);
        uint2 c8 = sCat[i];
        #pragma unroll
        for (int k = 0; k < 8; ++k) {
            unsigned c = ((k < 4 ? (c8.x >> (8 * k)) : (c8.y >> (8 * (k - 4)))) & 255u);
            uint2 nv = sNe2[c * 34 + dg];
            acc[k][0] += fmaxf(hv.x + bf_lo(nv.x), 0.f);
            acc[k][1] += fmaxf(hv.y + bf_hi(nv.x), 0.f);
            acc[k][2] += fmaxf(hv.z + bf_lo(nv.y), 0.f);
            acc[k][3] += fmaxf(hv.w + bf_hi(nv.y), 0.f);
        }
    }
    // merge the wave's two src subgroups (lane ^ 32) -> 8 partial groups (1/wave)
    #pragma unroll
    for (int k = 0; k < 8; ++k)
        #pragma unroll
        for (int d = 0; d < 4; ++d)
            acc[k][d] += __shfl_xor(acc[k][d], 32);
    // half-wave 0 stores rows 0..3, half-wave 1 stores rows 4..7
    {
        int hw = (t >> 5) & 1;
        #pragma unroll
        for (int q = 0; q < 4; ++q) {
            int r = hw * 4 + q;
            *(float4*)&sPart[(w * 8 + r) * 128 + dg * 4] =
                make_float4(acc[r][0], acc[r][1], acc[r][2], acc[r][3]);
        }
    }
    __syncthreads();

    // ---- combine 8 partials + u=(1+eps)h + bf16 pack (512-exact phase) ----
    {
        int dim = t & 127, q = t >> 7;            // row pair (2q, 2q+1)
        const float eps1 = 1.0f + epsp[0];
        int r0 = 2 * q, r1 = 2 * q + 1;
        float u0 = eps1 * hb[(jb * 8 + r0) * HID + dim];
        float u1 = eps1 * hb[(jb * 8 + r1) * HID + dim];
        #pragma unroll
        for (int g = 0; g < 8; ++g) {
            u0 += sPart[(g * 8 + r0) * 128 + dim];
            u1 += sPart[(g * 8 + r1) * 128 + dim];
        }
        ((unsigned*)sUT)[dim * 4 + q] = pack_bf16(u0, u1);
    }
    __syncthreads();

    // ---- GEMM1: k-split 4, 8 rows, transposed-bf16 A, partials in sPart ----
    {
        const int dd = t & 127, ks = t >> 7;
        float a8[8] = {0.f,0.f,0.f,0.f,0.f,0.f,0.f,0.f};
        #pragma unroll 8
        for (int k = 0; k < 32; ++k) {
            int kk = ks * 32 + k;
            uint4 ax = sUT[kk];
            float wv = W1[kk * 128 + dd];
            a8[0] = fmaf(bf_lo(ax.x), wv, a8[0]);
            a8[1] = fmaf(bf_hi(ax.x), wv, a8[1]);
            a8[2] = fmaf(bf_lo(ax.y), wv, a8[2]);
            a8[3] = fmaf(bf_hi(ax.y), wv, a8[3]);
            a8[4] = fmaf(bf_lo(ax.z), wv, a8[4]);
            a8[5] = fmaf(bf_hi(ax.z), wv, a8[5]);
            a8[6] = fmaf(bf_lo(ax.w), wv, a8[6]);
            a8[7] = fmaf(bf_hi(ax.w), wv, a8[7]);
        }
        #pragma unroll
        for (int r = 0; r < 8; ++r) sPart[(ks * 8 + r) * 128 + dd] = a8[r];
    }
    __syncthreads();

    // ---- LN1 + relu (bias + k-split sum folded in); wave w -> row w ----
    {
        float aa = b1[lane] + sPart[w * 128 + lane] + sPart[(8 + w) * 128 + lane] +
                   sPart[(16 + w) * 128 + lane] + sPart[(24 + w) * 128 + lane];
        float cc = b1[lane + 64] + sPart[w * 128 + lane + 64] + sPart[(8 + w) * 128 + lane + 64] +
                   sPart[(16 + w) * 128 + lane + 64] + sPart[(24 + w) * 128 + lane + 64];
        float mean, rs; ln_stats(aa, cc, mean, rs);
        sH1[w][lane]      = fmaxf((aa - mean) * rs * g1[lane]      + bt1[lane],      0.f);
        sH1[w][lane + 64] = fmaxf((cc - mean) * rs * g1[lane + 64] + bt1[lane + 64], 0.f);
    }
    __syncthreads();

    // ---- pack h1 transposed bf16 (512-exact) ----
    {
        int dim = t & 127, q = t >> 7;
        ((unsigned*)sH1T)[dim * 4 + q] = pack_bf16(sH1[2 * q][dim], sH1[2 * q + 1][dim]);
    }
    __syncthreads();

    // ---- GEMM2 ----
    {
        const int dd = t & 127, ks = t >> 7;
        float a8[8] = {0.f,0.f,0.f,0.f,0.f,0.f,0.f,0.f};
        #pragma unroll 8
        for (int k = 0; k < 32; ++k) {
            int kk = ks * 32 + k;
            uint4 ax = sH1T[kk];
            float wv = W2[kk * 128 + dd];
            a8[0] = fmaf(bf_lo(ax.x), wv, a8[0]);
            a8[1] = fmaf(bf_hi(ax.x), wv, a8[1]);
            a8[2] = fmaf(bf_lo(ax.y), wv, a8[2]);
            a8[3] = fmaf(bf_hi(ax.y), wv, a8[3]);
            a8[4] = fmaf(bf_lo(ax.z), wv, a8[4]);
            a8[5] = fmaf(bf_hi(ax.z), wv, a8[5]);
            a8[6] = fmaf(bf_lo(ax.w), wv, a8[6]);
            a8[7] = fmaf(bf_hi(ax.w), wv, a8[7]);
        }
        #pragma unroll
        for (int r = 0; r < 8; ++r) sPart[(ks * 8 + r) * 128 + dd] = a8[r];
    }
    __syncthreads();

    // ---- LN2 (bias+sum folded) -> LN3 + relu + residual -> store ----
    {
        float aa = b2[lane] + sPart[w * 128 + lane] + sPart[(8 + w) * 128 + lane] +
                   sPart[(16 + w) * 128 + lane] + sPart[(24 + w) * 128 + lane];
        float cc = b2[lane + 64] + sPart[w * 128 + lane + 64] + sPart[(8 + w) * 128 + lane + 64] +
                   sPart[(16 + w) * 128 + lane + 64] + sPart[(24 + w) * 128 + lane + 64];
        float mean, rs; ln_stats(aa, cc, mean, rs);
        float y1 = (aa - mean) * rs * g2[lane]      + bt2[lane];
        float y2 = (cc - mean) * rs * g2[lane + 64] + bt2[lane + 64];

        float mean3, rs3; ln_stats(y1, y2, mean3, rs3);
        int row = jb * 8 + w;
        int grow = b * NN + row;
        float ho1 = hb[row * HID + lane], ho2 = hb[row * HID + lane + 64];
        float z1 = fmaxf((y1 - mean3) * rs3 * lng[lane]      + lnb[lane],      0.f) + ho1;
        float z2 = fmaxf((y2 - mean3) * rs3 * lng[lane + 64] + lnb[lane + 64], 0.f) + ho2;

        if (!isLast) {
            h_new[(size_t)grow * HID + lane]      = z1;
            h_new[(size_t)grow * HID + lane + 64] = z2;
        } else {
            #pragma unroll
            for (int ccx = 0; ccx < 3; ++ccx) {
                float p = z1 * outW[lane * 3 + ccx] + z2 * outW[(lane + 64) * 3 + ccx];
                #pragma unroll
                for (int m = 32; m; m >>= 1) p += __shfl_xor(p, m);
                if (lane == 0) dout[grow * 3 + ccx] = p + outb[ccx];
            }
        }
    }
}

// ---------------------------------------------------------------------------
extern "C" void kernel_launch(void* const* d_in, const int* in_sizes, int n_in,
                              void* d_out, int out_size, void* d_ws, size_t ws_size,
                              hipStream_t stream) {
    const float* x     = (const float*)d_in[0];
    const float* emb   = (const float*)d_in[1];
    const float* inW1  = (const float*)d_in[2];
    const float* inb1  = (const float*)d_in[3];
    const float* ing1  = (const float*)d_in[4];
    const float* inbt1 = (const float*)d_in[5];
    const float* inW2  = (const float*)d_in[6];
    const float* inb2  = (const float*)d_in[7];
    const float* ing2  = (const float*)d_in[8];
    const float* inbt2 = (const float*)d_in[9];
    const float* cW1   = (const float*)d_in[10];
    const float* cb1   = (const float*)d_in[11];
    const float* cg1   = (const float*)d_in[12];
    const float* cbt1  = (const float*)d_in[13];
    const float* cW2   = (const float*)d_in[14];
    const float* cb2   = (const float*)d_in[15];
    const float* cg2   = (const float*)d_in[16];
    const float* cbt2  = (const float*)d_in[17];
    const float* ceps  = (const float*)d_in[18];
    const float* lng   = (const float*)d_in[19];
    const float* lnb   = (const float*)d_in[20];
    const float* outW  = (const float*)d_in[21];
    const float* outb  = (const float*)d_in[22];
    const int*   ecat  = (const int*)d_in[25];

    float* ws      = (float*)d_ws;
    unsigned* nep  = (unsigned*)ws;             // 4096 u32 (16 KB bf16 ne)
    uint2* catp    = (uint2*)(ws + 4096);       // 8192 uint2 (16384 float slots)
    float* hA   = ws + 4096 + 16384;            // B*N*HID
    float* hB   = hA + BB * NN * HID;
    float* out  = (float*)d_out;

    k_setup<<<296, 512, 0, stream>>>(x, emb, inW1, inb1, ing1, inbt1,
                                     inW2, inb2, ing2, inbt2, ecat, nep, catp, hA);

    for (int l = 0; l < 4; ++l) {
        const float* ho = (l & 1) ? hB : hA;
        float*       hn = (l & 1) ? hA : hB;
        k_layer<<<256, 512, 0, stream>>>(
            ho, hn, (const uint4*)nep, catp,
            cW1 + l * HID * HID, cb1 + l * HID, cg1 + l * HID, cbt1 + l * HID,
            cW2 + l * HID * HID, cb2 + l * HID, cg2 + l * HID, cbt2 + l * HID,
            ceps + l, lng + l * HID, lnb + l * HID,
            outW, outb, out, (l == 3) ? 1 : 0);
    }
}